// Round 8
// baseline (238.162 us; speedup 1.0000x reference)
//
#include <hip/hip_runtime.h>
#include <hip/hip_bf16.h>
#include <math.h>

#define SEQ 2048
#define ND  1024
#define NH  16
#define HD  64
#define NPOSN 64

typedef short short8 __attribute__((ext_vector_type(8)));
typedef short short4v __attribute__((ext_vector_type(4)));
typedef float floatx4 __attribute__((ext_vector_type(4)));

#define MFMA16(A, B, C) __builtin_amdgcn_mfma_f32_16x16x32_bf16((A), (B), (C), 0, 0, 0)

#define ASYNC16(gp, lp)                                                                     \
  __builtin_amdgcn_global_load_lds((const __attribute__((address_space(1))) unsigned int*)(gp), \
                                   (__attribute__((address_space(3))) unsigned int*)(lp), 16, 0, 0)

__device__ __forceinline__ short f2bf(float x) {
  __hip_bfloat16 h = __float2bfloat16(x);
  return *reinterpret_cast<short*>(&h);
}
__device__ __forceinline__ float bf2f(short s) {
  __hip_bfloat16 h = *reinterpret_cast<__hip_bfloat16*>(&s);
  return __bfloat162float(h);
}
__device__ __forceinline__ float lane_bcast(float v, int l) {
  return __int_as_float(__builtin_amdgcn_readlane(__float_as_int(v), l));
}

// ---------------------------------------------------------------------------
// prep: fp32 -> separate bf16 hi/lo planes (K=1024 rows).
// z 0..2: activations q,k,v (2048 rows); z 3..6: weights (1024 rows); z 7: peT.
// ---------------------------------------------------------------------------
struct Prep2 {
  const float* x0; short* x0h; short* x0l;
  const float* x1; short* x1h; short* x1l;
  const float* x2; short* x2h; short* x2l;
  const float* w0; short* w0h; short* w0l;
  const float* w1; short* w1h; short* w1l;
  const float* w2; short* w2h; short* w2l;
  const float* w3; short* w3h; short* w3l;
  const float* pe; short* peT;
};

__device__ __forceinline__ void split_planes(const float* __restrict__ in,
                                             short* __restrict__ oh,
                                             short* __restrict__ ol) {
  int r = blockIdx.x;
  int c = threadIdx.x << 2;
  float4 v = *(const float4*)(in + (size_t)r * 1024 + c);
  short4v hi, lo;
  hi.x = f2bf(v.x); lo.x = f2bf(v.x - bf2f(hi.x));
  hi.y = f2bf(v.y); lo.y = f2bf(v.y - bf2f(hi.y));
  hi.z = f2bf(v.z); lo.z = f2bf(v.z - bf2f(hi.z));
  hi.w = f2bf(v.w); lo.w = f2bf(v.w - bf2f(hi.w));
  *(short4v*)(oh + (size_t)r * 1024 + c) = hi;
  *(short4v*)(ol + (size_t)r * 1024 + c) = lo;
}

__global__ __launch_bounds__(256)
void prep2(Prep2 P) {
  const int z = blockIdx.z;
  if (z < 3) {
    const float* in = (z == 0) ? P.x0 : (z == 1 ? P.x1 : P.x2);
    short* oh = (z == 0) ? P.x0h : (z == 1 ? P.x1h : P.x2h);
    short* ol = (z == 0) ? P.x0l : (z == 1 ? P.x1l : P.x2l);
    split_planes(in, oh, ol);
  } else if (z < 7) {
    if (blockIdx.x >= 1024) return;
    const float* in = (z == 3) ? P.w0 : (z == 4 ? P.w1 : (z == 5 ? P.w2 : P.w3));
    short* oh = (z == 3) ? P.w0h : (z == 4 ? P.w1h : (z == 5 ? P.w2h : P.w3h));
    short* ol = (z == 3) ? P.w0l : (z == 4 ? P.w1l : (z == 5 ? P.w2l : P.w3l));
    split_planes(in, oh, ol);
  } else {
    if (blockIdx.x != 0) return;
    for (int i = threadIdx.x; i < 4096; i += 256) {
      int n = i >> 6, d = i & 63;
      P.peT[n * 64 + d] = f2bf(P.pe[d * 64 + n]);   // peT[npos][d]
    }
  }
}

// ---------------------------------------------------------------------------
// Plane-split MFMA GEMM, BK=32 DOUBLE-BUFFERED (m97-style: DMA for iter t+1
// issued under compute of iter t, single barrier per iter).
// C[M,N] = X[M,1024]·W[N,1024]^T + bias
// 3-term (Blo != null): Ahi·Bhi + Alo·Bhi + Ahi·Blo
// 2-term (Blo == null): Ahi·Bhi + Alo·Bhi  (exact-X · Whi)
// Tile 128x64. mode 0: fp32 [M][1024]; mode 1: head bf16 [h][m][64];
// mode 2: head transposed [h][64][m]. o1==null -> skip lo store.
// ---------------------------------------------------------------------------
struct GArg2 {
  const short* Ahi; const short* Alo;
  const short* Bhi; const short* Blo;
  const float* bias;
  void* o0; void* o1; int mode;
};

__global__ __launch_bounds__(256, 3)
void gemm_planes(GArg2 ga, GArg2 gb, GArg2 gc) {
  __shared__ __align__(16) short Ah[2][4096];   // 128 rows x 32 k
  __shared__ __align__(16) short Al[2][4096];
  __shared__ __align__(16) short Bh[2][2048];   // 64 rows x 32 k
  __shared__ __align__(16) short Bl[2][2048];
  GArg2 A = (blockIdx.z == 0) ? ga : ((blockIdx.z == 1) ? gb : gc);
  const bool t3 = (A.Blo != nullptr);
  const int t = threadIdx.x;
  const int w = t >> 6, lane = t & 63;
  const int col = lane & 15, quad = lane >> 4;
  const int m0 = blockIdx.x * 128, n0 = blockIdx.y * 64;
  const int wr = (w & 1) * 64, wc = (w >> 1) * 32;
  const int r16 = lane >> 2;                 // row within 16
  const int chnk = (lane & 3) ^ (r16 & 3);   // XOR-swizzled source chunk (4x16B/row)

  auto stage = [&](int k, int buf) {
    const int kk = k * 32;
#pragma unroll
    for (int i = 0; i < 2; ++i) {
      const int inst = 2 * w + i;            // 0..7
      const int row = inst * 16 + r16;
      ASYNC16(A.Ahi + (size_t)(m0 + row) * 1024 + kk + chnk * 8, &Ah[buf][inst * 512]);
      ASYNC16(A.Alo + (size_t)(m0 + row) * 1024 + kk + chnk * 8, &Al[buf][inst * 512]);
    }
    {
      const int row = w * 16 + r16;
      ASYNC16(A.Bhi + (size_t)(n0 + row) * 1024 + kk + chnk * 8, &Bh[buf][w * 512]);
      if (t3) ASYNC16(A.Blo + (size_t)(n0 + row) * 1024 + kk + chnk * 8, &Bl[buf][w * 512]);
    }
  };

  floatx4 acc[4][2] = {};
  stage(0, 0);
#pragma unroll 1
  for (int it = 0; it < 32; ++it) {
    const int buf = it & 1;
    __syncthreads();                          // drains DMA into buf, guards buf^1 reuse
    if (it < 31) stage(it + 1, buf ^ 1);
    short8 ah[4], al[4], bh[2], bl[2];
#pragma unroll
    for (int mt = 0; mt < 4; ++mt) {
      const int row = wr + mt * 16 + col;
      const int pos = (quad ^ (row & 3)) * 8;
      ah[mt] = *(const short8*)&Ah[buf][row * 32 + pos];
      al[mt] = *(const short8*)&Al[buf][row * 32 + pos];
    }
#pragma unroll
    for (int nt = 0; nt < 2; ++nt) {
      const int row = wc + nt * 16 + col;
      const int pos = (quad ^ (row & 3)) * 8;
      bh[nt] = *(const short8*)&Bh[buf][row * 32 + pos];
      if (t3) bl[nt] = *(const short8*)&Bl[buf][row * 32 + pos];
    }
#pragma unroll
    for (int mt = 0; mt < 4; ++mt)
#pragma unroll
      for (int nt = 0; nt < 2; ++nt) {
        acc[mt][nt] = MFMA16(ah[mt], bh[nt], acc[mt][nt]);
        acc[mt][nt] = MFMA16(al[mt], bh[nt], acc[mt][nt]);
        if (t3) acc[mt][nt] = MFMA16(ah[mt], bl[nt], acc[mt][nt]);
      }
  }
#pragma unroll
  for (int nt = 0; nt < 2; ++nt) {
    const int n = n0 + wc + nt * 16 + col;
    const float bb = A.bias[n];
#pragma unroll
    for (int mt = 0; mt < 4; ++mt)
#pragma unroll
      for (int r = 0; r < 4; ++r) {
        const int m = m0 + wr + mt * 16 + quad * 4 + r;
        const float v = acc[mt][nt][r] + bb;
        if (A.mode == 0) {
          ((float*)A.o0)[(size_t)m * 1024 + n] = v;
        } else {
          const short hi = f2bf(v);
          const int hh = n >> 6, d = n & 63;
          const size_t off = (A.mode == 1) ? ((size_t)(hh * SEQ + m) * 64 + d)
                                           : ((size_t)(hh * 64 + d) * SEQ + m);
          ((short*)A.o0)[off] = hi;
          if (A.o1) {
            const short lo = f2bf(v - bf2f(hi));
            ((short*)A.o1)[off] = lo;
          }
        }
      }
  }
}

// ---------------------------------------------------------------------------
// Flash CoPE attention v5. 256-thr blocks = 4 waves x 16 q-rows (64-q block).
// K/V tiles LDS-staged via DMA (double-buffered, XOR-swizzled). Key tiles
// last->first. CLAMP FAST-PATH (carry >= 63 -> cope = lis[63] exactly).
// PV SOFTWARE-PIPELINED by one iteration: Phi double-buffered, V fragments
// carried in registers, so the P transpose write->read never stalls in-iter
// and PV MFMAs overlap the exp/softmax VALU chain.
// ---------------------------------------------------------------------------
__global__ __launch_bounds__(256, 2)
void cope_attn_mfma(const short* __restrict__ Qhi, const short* __restrict__ Qlo,
                    const short* __restrict__ Khi, const short* __restrict__ Vthi,
                    const short* __restrict__ peT,
                    short* __restrict__ AOhi, short* __restrict__ AOlo) {
  __shared__ __align__(16) short Klds[2][4096];
  __shared__ __align__(16) short Vlds[2][4096];
  __shared__ __align__(16) short Phi[2][4][16][64];  // [pbuf][wave][qrow][key^swz]
  __shared__ int lisP[4][16][64];                    // bf16 pair (lis[p], lis[p+1])
  __shared__ float lis63s[4][16];
  const int tid = threadIdx.x;
  const int w = tid >> 6, lane = tid & 63;
  const int col = lane & 15, quad = lane >> 4;
  const int h = blockIdx.x & 15;
  const int q0 = (blockIdx.x >> 4) * 64 + w * 16;

  const short* Kb = Khi + (size_t)h * SEQ * 64;
  const short* Vb = Vthi + (size_t)h * 64 * SEQ;

  const int lrow8 = lane >> 3;
  const int src_c = (lane & 7) ^ lrow8;
  const int swz = col & 7;

  auto stage = [&](int kt, int buf) {
#pragma unroll
    for (int i = 0; i < 2; ++i) {
      const int inst = 2 * w + i;
      const int row = inst * 8 + lrow8;
      ASYNC16(Kb + (size_t)(kt * 64 + row) * 64 + src_c * 8, &Klds[buf][inst * 512]);
      ASYNC16(Vb + (size_t)row * SEQ + kt * 64 + src_c * 8, &Vlds[buf][inst * 512]);
    }
  };

  short8 qB[2][2];
#pragma unroll
  for (int ks = 0; ks < 2; ++ks) {
    qB[ks][0] = *(const short8*)(Qhi + (size_t)(h * SEQ + q0 + col) * 64 + ks * 32 + quad * 8);
    qB[ks][1] = *(const short8*)(Qlo + (size_t)(h * SEQ + q0 + col) * 64 + ks * 32 + quad * 8);
  }

  stage(31, 0);

  // logits_int = Q · pos_emb -> bf16-pair table + fp32 lis[63]
  {
    floatx4 li[4] = {};
#pragma unroll
    for (int nt = 0; nt < 4; ++nt)
#pragma unroll
      for (int ks = 0; ks < 2; ++ks) {
        short8 pb = *(const short8*)(peT + (nt * 16 + col) * 64 + ks * 32 + quad * 8);
        li[nt] = MFMA16(qB[ks][0], pb, li[nt]);
        li[nt] = MFMA16(qB[ks][1], pb, li[nt]);
      }
#pragma unroll
    for (int nt = 0; nt < 4; ++nt)
#pragma unroll
      for (int r = 0; r < 4; ++r) {
        const int qr = quad * 4 + r;
        const int pos = nt * 16 + col;
        const float v = li[nt][r];
        const short bv = f2bf(v);
        short* sp = (short*)&lisP[w][qr][0];
        sp[2 * pos] = bv;                       // low half of int[pos]
        if (pos > 0) sp[2 * pos - 1] = bv;      // high half of int[pos-1]
        if (pos == 63) { sp[127] = bv; lis63s[w][qr] = v; }
      }
  }
  __syncthreads();   // staging(31) drained + tables ready
  const float lis63 = lis63s[w][col];

  float lrow = 0.f;
  float carry = 0.f;
  bool fast = false;
  floatx4 O[4] = {};
  short8 vfs[2][4];   // V fragments carried to next iteration

#pragma unroll 1
  for (int it = 0; it < 32; ++it) {
    const int kt = 31 - it;
    const int buf = it & 1;
    const int pb = it & 1;
    if (kt > 0) stage(kt - 1, buf ^ 1);

    // K fragments for this tile
    short8 kf[4][2];
#pragma unroll
    for (int ksub = 0; ksub < 4; ++ksub)
#pragma unroll
      for (int ks = 0; ks < 2; ++ks)
        kf[ksub][ks] =
            *(const short8*)&Klds[buf][(ksub * 16 + col) * 64 + (((ks * 4 + quad) ^ swz) * 8)];

    // QK (K hi · Q split)
    floatx4 S[4] = {};
#pragma unroll
    for (int ksub = 0; ksub < 4; ++ksub)
#pragma unroll
      for (int ks = 0; ks < 2; ++ks) {
        S[ksub] = MFMA16(kf[ksub][ks], qB[ks][0], S[ksub]);
        S[ksub] = MFMA16(kf[ksub][ks], qB[ks][1], S[ksub]);
      }

    // PV of PREVIOUS tile (overlaps the softmax chain below)
    if (it > 0) {
      short8 pa[2];
#pragma unroll
      for (int ks = 0; ks < 2; ++ks)
        pa[ks] = *(const short8*)&Phi[pb ^ 1][w][col][((ks * 4 + quad) ^ swz) * 8];
#pragma unroll
      for (int ks = 0; ks < 2; ++ks)
#pragma unroll
        for (int dt = 0; dt < 4; ++dt)
          O[dt] = MFMA16(pa[ks], vfs[ks][dt], O[dt]);
    }

    float sv[4][4];
#pragma unroll
    for (int ksub = 0; ksub < 4; ++ksub)
#pragma unroll
      for (int r = 0; r < 4; ++r) sv[ksub][r] = S[ksub][r] * 0.125f;

    if (!fast && __all((int)(carry >= 63.0f))) fast = true;

    float p4[4][4];
    if (fast) {
#pragma unroll
      for (int ksub = 0; ksub < 4; ++ksub)
#pragma unroll
        for (int r = 0; r < 4; ++r) {
          float pr = __expf(sv[ksub][r] + lis63);
          p4[ksub][r] = pr;
          lrow += pr;
        }
    } else {
      float g[4][4];
#pragma unroll
      for (int ksub = 0; ksub < 4; ++ksub)
#pragma unroll
        for (int r = 0; r < 4; ++r)
          g[ksub][r] = __builtin_amdgcn_rcpf(1.0f + __expf(-sv[ksub][r]));
      float l[4][4], S4[4];
#pragma unroll
      for (int ksub = 0; ksub < 4; ++ksub) {
        l[ksub][3] = g[ksub][3];
        l[ksub][2] = l[ksub][3] + g[ksub][2];
        l[ksub][1] = l[ksub][2] + g[ksub][1];
        l[ksub][0] = l[ksub][1] + g[ksub][0];
        S4[ksub] = l[ksub][0];
      }
      float Sq[4], T[4];
#pragma unroll
      for (int ksub = 0; ksub < 4; ++ksub) {
        float d16 = __shfl_down(S4[ksub], 16, 64);
        float d32 = __shfl_down(S4[ksub], 32, 64);
        float d48 = __shfl_down(S4[ksub], 48, 64);
        float u16 = __shfl_up(S4[ksub], 16, 64);
        float u32 = __shfl_up(S4[ksub], 32, 64);
        float u48 = __shfl_up(S4[ksub], 48, 64);
        float sq = ((quad < 3) ? d16 : 0.f) + ((quad < 2) ? d32 : 0.f) + ((quad < 1) ? d48 : 0.f);
        float pq = ((quad > 0) ? u16 : 0.f) + ((quad > 1) ? u32 : 0.f) + ((quad > 2) ? u48 : 0.f);
        Sq[ksub] = sq;
        T[ksub] = pq + S4[ksub] + sq;
      }
      float U[4];
      U[3] = carry;
      U[2] = U[3] + T[3];
      U[1] = U[2] + T[2];
      U[0] = U[1] + T[1];
      carry = U[0] + T[0];
#pragma unroll
      for (int ksub = 0; ksub < 4; ++ksub)
#pragma unroll
        for (int r = 0; r < 4; ++r) {
          float p = fminf(U[ksub] + Sq[ksub] + l[ksub][r], 63.0f);
          float pf = floorf(p);
          int fi = (int)pf;
          float wq = p - pf;
          int pp = lisP[w][col][fi];
          float lf = bf2f((short)(pp & 0xffff));
          float lc = bf2f((short)((unsigned)pp >> 16));
          float pr = __expf(sv[ksub][r] + lf + wq * (lc - lf));
          p4[ksub][r] = pr;
          lrow += pr;
        }
    }

    // write P (bf16 pairs) into this iter's Phi buffer (consumed next iter)
#pragma unroll
    for (int ksub = 0; ksub < 4; ++ksub)
#pragma unroll
      for (int rp = 0; rp < 2; ++rp) {
        short h0 = f2bf(p4[ksub][2 * rp]);
        short h1 = f2bf(p4[ksub][2 * rp + 1]);
        const int posi = ksub * 16 + quad * 4 + 2 * rp;
        const int addr = (((posi >> 3) ^ swz) << 3) + (posi & 7);
        *(int*)&Phi[pb][w][col][addr] =
            (unsigned short)h0 | ((unsigned)(unsigned short)h1 << 16);
      }

    // V fragments for THIS tile (consumed next iter)
#pragma unroll
    for (int ks = 0; ks < 2; ++ks)
#pragma unroll
      for (int dt = 0; dt < 4; ++dt)
        vfs[ks][dt] =
            *(const short8*)&Vlds[buf][(dt * 16 + col) * 64 + (((ks * 4 + quad) ^ swz) * 8)];

    __syncthreads();   // all waves done with buf; stage(kt-1) drained here
  }

  // drain the pipeline: PV of the last tile (Phi[1], vfs from it=31)
  {
    short8 pa[2];
#pragma unroll
    for (int ks = 0; ks < 2; ++ks)
      pa[ks] = *(const short8*)&Phi[1][w][col][((ks * 4 + quad) ^ swz) * 8];
#pragma unroll
    for (int ks = 0; ks < 2; ++ks)
#pragma unroll
      for (int dt = 0; dt < 4; ++dt)
        O[dt] = MFMA16(pa[ks], vfs[ks][dt], O[dt]);
  }

  // epilogue: reduce lrow, normalize, write AO hi/lo planes
  float lr = lrow;
  lr += __shfl_xor(lr, 16, 64);
  lr += __shfl_xor(lr, 32, 64);
  float inv[4];
#pragma unroll
  for (int r = 0; r < 4; ++r) inv[r] = 1.0f / __shfl(lr, quad * 4 + r, 64);
#pragma unroll
  for (int dt = 0; dt < 4; ++dt)
#pragma unroll
    for (int r = 0; r < 4; ++r) {
      float val = O[dt][r] * inv[r];
      int q = q0 + quad * 4 + r;
      int cg = h * 64 + dt * 16 + col;
      short hi = f2bf(val), lo = f2bf(val - bf2f(hi));
      AOhi[(size_t)q * 1024 + cg] = hi;
      AOlo[(size_t)q * 1024 + cg] = lo;
    }
}

// ---------------------------------------------------------------------------
// fp32 fallback (used only if ws_size is too small)
// ---------------------------------------------------------------------------
template <int MODE>
__global__ __launch_bounds__(256)
void gemm_bt_f32(const float* __restrict__ X, const float* __restrict__ W,
                 const float* __restrict__ bias, float* __restrict__ C,
                 int M, int N, int K) {
  __shared__ __align__(16) float Xs[16][68];
  __shared__ __align__(16) float Ws[16][68];
  const int t = threadIdx.x;
  const int tx = t & 15, ty = t >> 4;
  const int m0 = blockIdx.x * 64, n0 = blockIdx.y * 64;
  const int r = t >> 2;
  const int c4 = (t & 3) << 2;
  const float* Xp = X + (size_t)(m0 + r) * K + c4;
  const float* Wp = W + (size_t)(n0 + r) * K + c4;
  float acc[4][4] = {};
  for (int k0 = 0; k0 < K; k0 += 16) {
    float4 xv = *(const float4*)(Xp + k0);
    float4 wv = *(const float4*)(Wp + k0);
    __syncthreads();
    Xs[c4 + 0][r] = xv.x; Xs[c4 + 1][r] = xv.y; Xs[c4 + 2][r] = xv.z; Xs[c4 + 3][r] = xv.w;
    Ws[c4 + 0][r] = wv.x; Ws[c4 + 1][r] = wv.y; Ws[c4 + 2][r] = wv.z; Ws[c4 + 3][r] = wv.w;
    __syncthreads();
#pragma unroll
    for (int k = 0; k < 16; ++k) {
      const float4 xr = *(const float4*)&Xs[k][ty << 2];
      const float4 wr = *(const float4*)&Ws[k][tx << 2];
      const float xa[4] = {xr.x, xr.y, xr.z, xr.w};
      const float wa[4] = {wr.x, wr.y, wr.z, wr.w};
#pragma unroll
      for (int i = 0; i < 4; ++i)
#pragma unroll
        for (int j = 0; j < 4; ++j) acc[i][j] += xa[i] * wa[j];
    }
  }
#pragma unroll
  for (int i = 0; i < 4; ++i) {
    const int m = m0 + (ty << 2) + i;
#pragma unroll
    for (int j = 0; j < 4; ++j) {
      const int n = n0 + (tx << 2) + j;
      const float v = acc[i][j] + bias[n];
      if (MODE == 0) C[(size_t)m * N + n] = v;
      else { const int hh = n >> 6, d = n & 63; C[((size_t)hh * SEQ + m) * HD + d] = v; }
    }
  }
}

__global__ __launch_bounds__(256)
void cope_attn_f32(const float* __restrict__ Qh, const float* __restrict__ Kh,
                   const float* __restrict__ Vh, const float* __restrict__ pe,
                   float* __restrict__ AO) {
  __shared__ float Kt[64][65];
  __shared__ float Vt[64][65];
  __shared__ float lis[16][64];
  const int t = threadIdx.x;
  const int lane = t & 63;
  const int w = t >> 6;
  const int h = blockIdx.y;
  const int qbase = blockIdx.x * 16 + w * 4;
  float qreg[4];
#pragma unroll
  for (int rr = 0; rr < 4; ++rr)
    qreg[rr] = Qh[((size_t)h * SEQ + qbase + rr) * HD + lane];
  float li[4] = {0.f, 0.f, 0.f, 0.f};
  for (int d = 0; d < 64; ++d) {
    const float pv = pe[d * NPOSN + lane];
#pragma unroll
    for (int rr = 0; rr < 4; ++rr) li[rr] += lane_bcast(qreg[rr], d) * pv;
  }
#pragma unroll
  for (int rr = 0; rr < 4; ++rr) lis[w * 4 + rr][lane] = li[rr];
  float mrow[4] = {-1e30f, -1e30f, -1e30f, -1e30f};
  float lrow[4] = {0.f, 0.f, 0.f, 0.f};
  float carry[4] = {0.f, 0.f, 0.f, 0.f};
  float acc[4] = {0.f, 0.f, 0.f, 0.f};
  for (int kt = (SEQ / 64) - 1; kt >= 0; --kt) {
    const int k0 = kt * 64;
    __syncthreads();
#pragma unroll
    for (int i = 0; i < 4; ++i) {
      const int lin = t + i * 256;
      const int row = lin >> 4, cc = (lin & 15) << 2;
      const float4 kv = *(const float4*)(Kh + ((size_t)h * SEQ + k0 + row) * HD + cc);
      Kt[row][cc + 0] = kv.x; Kt[row][cc + 1] = kv.y; Kt[row][cc + 2] = kv.z; Kt[row][cc + 3] = kv.w;
      const float4 vv = *(const float4*)(Vh + ((size_t)h * SEQ + k0 + row) * HD + cc);
      Vt[row][cc + 0] = vv.x; Vt[row][cc + 1] = vv.y; Vt[row][cc + 2] = vv.z; Vt[row][cc + 3] = vv.w;
    }
    __syncthreads();
    float svv[4] = {0.f, 0.f, 0.f, 0.f};
#pragma unroll
    for (int d = 0; d < 64; ++d) {
      const float kd = Kt[lane][d];
#pragma unroll
      for (int rr = 0; rr < 4; ++rr) svv[rr] += lane_bcast(qreg[rr], d) * kd;
    }
    float p4[4], scl[4];
#pragma unroll
    for (int rr = 0; rr < 4; ++rr) {
      const float s = svv[rr] * 0.125f;
      const float gg = 1.0f / (1.0f + __expf(-s));
      float gs = gg;
#pragma unroll
      for (int off = 1; off < 64; off <<= 1) {
        const float tt = __shfl_down(gs, off, 64);
        gs += (lane + off < 64) ? tt : 0.0f;
      }
      const float tot = lane_bcast(gs, 0);
      float p = carry[rr] + gs;
      carry[rr] += tot;
      p = fminf(p, 63.0f);
      const float pf = floorf(p);
      const float wq = p - pf;
      const int fi = (int)pf;
      const int ci = (int)ceilf(p);
      const float cope = lis[w * 4 + rr][ci] * wq + lis[w * 4 + rr][fi] * (1.0f - wq);
      const float av = s + cope;
      float mt = av;
#pragma unroll
      for (int off = 32; off > 0; off >>= 1) mt = fmaxf(mt, __shfl_xor(mt, off, 64));
      const float nm = fmaxf(mrow[rr], mt);
      const float sc = __expf(mrow[rr] - nm);
      const float p2 = __expf(av - nm);
      float psum = p2;
#pragma unroll
      for (int off = 32; off > 0; off >>= 1) psum += __shfl_xor(psum, off, 64);
      lrow[rr] = lrow[rr] * sc + psum;
      mrow[rr] = nm;
      p4[rr] = p2;
      scl[rr] = sc;
    }
#pragma unroll
    for (int rr = 0; rr < 4; ++rr) acc[rr] *= scl[rr];
#pragma unroll
    for (int j = 0; j < 64; ++j) {
      const float vj = Vt[j][lane];
#pragma unroll
      for (int rr = 0; rr < 4; ++rr) acc[rr] += lane_bcast(p4[rr], j) * vj;
    }
  }
#pragma unroll
  for (int rr = 0; rr < 4; ++rr)
    AO[(size_t)(qbase + rr) * ND + h * HD + lane] = acc[rr] / lrow[rr];
}

// ---------------------------------------------------------------------------
extern "C" void kernel_launch(void* const* d_in, const int* in_sizes, int n_in,
                              void* d_out, int out_size, void* d_ws, size_t ws_size,
                              hipStream_t stream) {
  (void)in_sizes; (void)n_in; (void)out_size;
  const float* q    = (const float*)d_in[0];
  const float* k    = (const float*)d_in[1];
  const float* v    = (const float*)d_in[2];
  const float* Wq_w = (const float*)d_in[3];
  const float* Wq_b = (const float*)d_in[4];
  const float* Wk_w = (const float*)d_in[5];
  const float* Wk_b = (const float*)d_in[6];
  const float* Wv_w = (const float*)d_in[7];
  const float* Wv_b = (const float*)d_in[8];
  const float* Wo_w = (const float*)d_in[9];
  const float* Wo_b = (const float*)d_in[10];
  const float* pe   = (const float*)d_in[11];
  float* out = (float*)d_out;
  char* ws = (char*)d_ws;

  const size_t XP = (size_t)SEQ * 1024 * 2;   // 4 MB per activation plane
  const size_t WP = (size_t)1024 * 1024 * 2;  // 2 MB per weight plane
  const size_t HB = (size_t)SEQ * 1024 * 2;   // 4 MB per head buffer
  const size_t NEED = 6 * XP + 8 * WP + 4 * HB + 8192;

  if (ws_size >= NEED) {
    short* Xqh = (short*)ws;               short* Xql = (short*)(ws + XP);
    short* Xkh = (short*)(ws + 2 * XP);    short* Xkl = (short*)(ws + 3 * XP);
    short* Xvh = (short*)(ws + 4 * XP);    short* Xvl = (short*)(ws + 5 * XP);
    char*  wb  = ws + 6 * XP;
    short* Wqh = (short*)wb;               short* Wql = (short*)(wb + WP);
    short* Wkh = (short*)(wb + 2 * WP);    short* Wkl = (short*)(wb + 3 * WP);
    short* Wvh = (short*)(wb + 4 * WP);    short* Wvl = (short*)(wb + 5 * WP);
    short* Woh = (short*)(wb + 6 * WP);    short* Wol = (short*)(wb + 7 * WP);
    char*  hb  = wb + 8 * WP;
    short* Qhi = (short*)hb;               short* Qlo = (short*)(hb + HB);
    short* Khi = (short*)(hb + 2 * HB);    short* Vthi = (short*)(hb + 3 * HB);
    short* peT = (short*)(hb + 4 * HB);
    short* AOhi = Xqh;                     // reuse after projections
    short* AOlo = Xql;

    Prep2 P{q, Xqh, Xql, k, Xkh, Xkl, v, Xvh, Xvl,
            Wq_w, Wqh, Wql, Wk_w, Wkh, Wkl, Wv_w, Wvh, Wvl, Wo_w, Woh, Wol,
            pe, peT};
    prep2<<<dim3(2048, 1, 8), 256, 0, stream>>>(P);
    GArg2 aq{Xqh, Xql, Wqh, Wql, Wq_b, Qhi, Qlo, 1};           // 3-term
    GArg2 ak{Xkh, Xkl, Wkh, nullptr, Wk_b, Khi, nullptr, 1};   // 2-term, hi only
    GArg2 av{Xvh, Xvl, Wvh, nullptr, Wv_b, Vthi, nullptr, 2};  // 2-term, transposed
    gemm_planes<<<dim3(16, 16, 3), 256, 0, stream>>>(aq, ak, av);
    cope_attn_mfma<<<512, 256, 0, stream>>>(Qhi, Qlo, Khi, Vthi, peT, AOhi, AOlo);
    GArg2 ao{AOhi, AOlo, Woh, Wol, Wo_b, (void*)out, nullptr, 0};   // 3-term fp32 out
    gemm_planes<<<dim3(16, 16, 1), 256, 0, stream>>>(ao, ao, ao);
  } else {
    const size_t per = (size_t)NH * SEQ * HD;
    float* Qh = (float*)d_ws;
    float* Kh = Qh + per;
    float* Vh = Kh + per;
    float* AO = Vh + per;
    dim3 gblk(256), ggrd(SEQ / 64, ND / 64);
    gemm_bt_f32<1><<<ggrd, gblk, 0, stream>>>(q, Wq_w, Wq_b, Qh, SEQ, ND, ND);
    gemm_bt_f32<1><<<ggrd, gblk, 0, stream>>>(k, Wk_w, Wk_b, Kh, SEQ, ND, ND);
    gemm_bt_f32<1><<<ggrd, gblk, 0, stream>>>(v, Wv_w, Wv_b, Vh, SEQ, ND, ND);
    cope_attn_f32<<<dim3(SEQ / 16, NH), 256, 0, stream>>>(Qh, Kh, Vh, pe, AO);
    gemm_bt_f32<0><<<ggrd, gblk, 0, stream>>>(AO, Wo_w, Wo_b, out, SEQ, ND, ND);
  }
}

// Round 9
// 202.992 us; speedup vs baseline: 1.1733x; 1.1733x over previous
//
#include <hip/hip_runtime.h>
#include <hip/hip_bf16.h>
#include <math.h>

#define SEQ 2048
#define ND  1024
#define NH  16
#define HD  64
#define NPOSN 64

typedef short short8 __attribute__((ext_vector_type(8)));
typedef short short4v __attribute__((ext_vector_type(4)));
typedef float floatx4 __attribute__((ext_vector_type(4)));

#define MFMA16(A, B, C) __builtin_amdgcn_mfma_f32_16x16x32_bf16((A), (B), (C), 0, 0, 0)

#define ASYNC16(gp, lp)                                                                     \
  __builtin_amdgcn_global_load_lds((const __attribute__((address_space(1))) unsigned int*)(gp), \
                                   (__attribute__((address_space(3))) unsigned int*)(lp), 16, 0, 0)

__device__ __forceinline__ short f2bf(float x) {
  __hip_bfloat16 h = __float2bfloat16(x);
  return *reinterpret_cast<short*>(&h);
}
__device__ __forceinline__ float bf2f(short s) {
  __hip_bfloat16 h = *reinterpret_cast<__hip_bfloat16*>(&s);
  return __bfloat162float(h);
}
__device__ __forceinline__ float lane_bcast(float v, int l) {
  return __int_as_float(__builtin_amdgcn_readlane(__float_as_int(v), l));
}

// ---------------------------------------------------------------------------
// prep: fp32 -> separate bf16 hi/lo planes (K=1024 rows).
// z 0..2: activations q,k,v (2048 rows); z 3..6: weights (1024 rows); z 7: peT.
// ---------------------------------------------------------------------------
struct Prep2 {
  const float* x0; short* x0h; short* x0l;
  const float* x1; short* x1h; short* x1l;
  const float* x2; short* x2h; short* x2l;
  const float* w0; short* w0h; short* w0l;
  const float* w1; short* w1h; short* w1l;
  const float* w2; short* w2h; short* w2l;
  const float* w3; short* w3h; short* w3l;
  const float* pe; short* peT;
};

__device__ __forceinline__ void split_planes(const float* __restrict__ in,
                                             short* __restrict__ oh,
                                             short* __restrict__ ol) {
  int r = blockIdx.x;
  int c = threadIdx.x << 2;
  float4 v = *(const float4*)(in + (size_t)r * 1024 + c);
  short4v hi, lo;
  hi.x = f2bf(v.x); lo.x = f2bf(v.x - bf2f(hi.x));
  hi.y = f2bf(v.y); lo.y = f2bf(v.y - bf2f(hi.y));
  hi.z = f2bf(v.z); lo.z = f2bf(v.z - bf2f(hi.z));
  hi.w = f2bf(v.w); lo.w = f2bf(v.w - bf2f(hi.w));
  *(short4v*)(oh + (size_t)r * 1024 + c) = hi;
  *(short4v*)(ol + (size_t)r * 1024 + c) = lo;
}

__global__ __launch_bounds__(256)
void prep2(Prep2 P) {
  const int z = blockIdx.z;
  if (z < 3) {
    const float* in = (z == 0) ? P.x0 : (z == 1 ? P.x1 : P.x2);
    short* oh = (z == 0) ? P.x0h : (z == 1 ? P.x1h : P.x2h);
    short* ol = (z == 0) ? P.x0l : (z == 1 ? P.x1l : P.x2l);
    split_planes(in, oh, ol);
  } else if (z < 7) {
    if (blockIdx.x >= 1024) return;
    const float* in = (z == 3) ? P.w0 : (z == 4 ? P.w1 : (z == 5 ? P.w2 : P.w3));
    short* oh = (z == 3) ? P.w0h : (z == 4 ? P.w1h : (z == 5 ? P.w2h : P.w3h));
    short* ol = (z == 3) ? P.w0l : (z == 4 ? P.w1l : (z == 5 ? P.w2l : P.w3l));
    split_planes(in, oh, ol);
  } else {
    if (blockIdx.x != 0) return;
    for (int i = threadIdx.x; i < 4096; i += 256) {
      int n = i >> 6, d = i & 63;
      P.peT[n * 64 + d] = f2bf(P.pe[d * 64 + n]);   // peT[npos][d]
    }
  }
}

// ---------------------------------------------------------------------------
// Plane-split MFMA GEMM (round-7 proven): BK=64 single-buffered, tile 128x64.
// 3-term (Blo != null): Ahi·Bhi + Alo·Bhi + Ahi·Blo
// 2-term (Blo == null): Ahi·Bhi + Alo·Bhi  (exact-X · Whi)
// mode 0: fp32 [M][1024]; mode 1: head bf16 [h][m][64]; mode 2: [h][64][m].
// ---------------------------------------------------------------------------
struct GArg2 {
  const short* Ahi; const short* Alo;
  const short* Bhi; const short* Blo;
  const float* bias;
  void* o0; void* o1; int mode;
};

__device__ __forceinline__ void gemm_store(const GArg2& A, int m, int n, float v) {
  if (A.mode == 0) {
    ((float*)A.o0)[(size_t)m * 1024 + n] = v;
  } else {
    const short hi = f2bf(v);
    const int hh = n >> 6, d = n & 63;
    const size_t off = (A.mode == 1) ? ((size_t)(hh * SEQ + m) * 64 + d)
                                     : ((size_t)(hh * 64 + d) * SEQ + m);
    ((short*)A.o0)[off] = hi;
    if (A.o1) {
      const short lo = f2bf(v - bf2f(hi));
      ((short*)A.o1)[off] = lo;
    }
  }
}

__global__ __launch_bounds__(256, 3)
void gemm_planes(GArg2 ga, GArg2 gb, GArg2 gc) {
  __shared__ __align__(16) short Ah[8192];   // 128 rows x 64 k
  __shared__ __align__(16) short Al[8192];
  __shared__ __align__(16) short Bh[4096];   // 64 rows x 64 k
  __shared__ __align__(16) short Bl[4096];
  GArg2 A = (blockIdx.z == 0) ? ga : ((blockIdx.z == 1) ? gb : gc);
  const bool t3 = (A.Blo != nullptr);
  const int t = threadIdx.x;
  const int w = t >> 6, lane = t & 63;
  const int col = lane & 15, quad = lane >> 4;
  const int m0 = blockIdx.x * 128, n0 = blockIdx.y * 64;
  const int wr = (w & 1) * 64, wc = (w >> 1) * 32;
  const int lrow8 = lane >> 3;
  const int src_c = (lane & 7) ^ lrow8;      // XOR-swizzled source chunk

  floatx4 acc[4][2] = {};
  for (int kk = 0; kk < 1024; kk += 64) {
#pragma unroll
    for (int i = 0; i < 4; ++i) {
      const int inst = 4 * w + i;
      const int row = inst * 8 + lrow8;
      ASYNC16(A.Ahi + (size_t)(m0 + row) * 1024 + kk + src_c * 8, &Ah[inst * 512]);
      ASYNC16(A.Alo + (size_t)(m0 + row) * 1024 + kk + src_c * 8, &Al[inst * 512]);
    }
#pragma unroll
    for (int i = 0; i < 2; ++i) {
      const int inst = 2 * w + i;
      const int row = inst * 8 + lrow8;
      ASYNC16(A.Bhi + (size_t)(n0 + row) * 1024 + kk + src_c * 8, &Bh[inst * 512]);
      if (t3) ASYNC16(A.Blo + (size_t)(n0 + row) * 1024 + kk + src_c * 8, &Bl[inst * 512]);
    }
    __syncthreads();
#pragma unroll
    for (int ks = 0; ks < 2; ++ks) {
      short8 ah[4], al[4], bh[2], bl[2];
#pragma unroll
      for (int mt = 0; mt < 4; ++mt) {
        const int row = wr + mt * 16 + col;
        const int pos = ((ks * 4 + quad) ^ (row & 7)) * 8;
        ah[mt] = *(const short8*)&Ah[row * 64 + pos];
        al[mt] = *(const short8*)&Al[row * 64 + pos];
      }
#pragma unroll
      for (int nt = 0; nt < 2; ++nt) {
        const int row = wc + nt * 16 + col;
        const int pos = ((ks * 4 + quad) ^ (row & 7)) * 8;
        bh[nt] = *(const short8*)&Bh[row * 64 + pos];
        if (t3) bl[nt] = *(const short8*)&Bl[row * 64 + pos];
      }
#pragma unroll
      for (int mt = 0; mt < 4; ++mt)
#pragma unroll
        for (int nt = 0; nt < 2; ++nt) {
          acc[mt][nt] = MFMA16(ah[mt], bh[nt], acc[mt][nt]);
          acc[mt][nt] = MFMA16(al[mt], bh[nt], acc[mt][nt]);
          if (t3) acc[mt][nt] = MFMA16(ah[mt], bl[nt], acc[mt][nt]);
        }
    }
    __syncthreads();
  }
#pragma unroll
  for (int nt = 0; nt < 2; ++nt) {
    const int n = n0 + wc + nt * 16 + col;
    const float bb = A.bias[n];
#pragma unroll
    for (int mt = 0; mt < 4; ++mt)
#pragma unroll
      for (int r = 0; r < 4; ++r)
        gemm_store(A, m0 + wr + mt * 16 + quad * 4 + r, n, acc[mt][nt][r] + bb);
  }
}

// 64x64-tile variant: 2x the blocks (512 for M=2048,N=1024) -> 2 blocks/CU for
// the final output GEMM whose 128-tile grid (256 blocks) was 1/CU-starved.
// Same plane-split math, same staging pattern, 32 KB LDS.
__global__ __launch_bounds__(256, 3)
void gemm_planes64(GArg2 A) {
  __shared__ __align__(16) short Ah[4096];   // 64 rows x 64 k
  __shared__ __align__(16) short Al[4096];
  __shared__ __align__(16) short Bh[4096];
  __shared__ __align__(16) short Bl[4096];
  const bool t3 = (A.Blo != nullptr);
  const int t = threadIdx.x;
  const int w = t >> 6, lane = t & 63;
  const int col = lane & 15, quad = lane >> 4;
  const int m0 = blockIdx.x * 64, n0 = blockIdx.y * 64;
  const int wr = (w & 1) * 32, wc = (w >> 1) * 32;
  const int lrow8 = lane >> 3;
  const int src_c = (lane & 7) ^ lrow8;

  floatx4 acc[2][2] = {};
  for (int kk = 0; kk < 1024; kk += 64) {
#pragma unroll
    for (int i = 0; i < 2; ++i) {
      const int inst = 2 * w + i;
      const int row = inst * 8 + lrow8;
      ASYNC16(A.Ahi + (size_t)(m0 + row) * 1024 + kk + src_c * 8, &Ah[inst * 512]);
      ASYNC16(A.Alo + (size_t)(m0 + row) * 1024 + kk + src_c * 8, &Al[inst * 512]);
      ASYNC16(A.Bhi + (size_t)(n0 + row) * 1024 + kk + src_c * 8, &Bh[inst * 512]);
      if (t3) ASYNC16(A.Blo + (size_t)(n0 + row) * 1024 + kk + src_c * 8, &Bl[inst * 512]);
    }
    __syncthreads();
#pragma unroll
    for (int ks = 0; ks < 2; ++ks) {
      short8 ah[2], al[2], bh[2], bl[2];
#pragma unroll
      for (int mt = 0; mt < 2; ++mt) {
        const int row = wr + mt * 16 + col;
        const int pos = ((ks * 4 + quad) ^ (row & 7)) * 8;
        ah[mt] = *(const short8*)&Ah[row * 64 + pos];
        al[mt] = *(const short8*)&Al[row * 64 + pos];
      }
#pragma unroll
      for (int nt = 0; nt < 2; ++nt) {
        const int row = wc + nt * 16 + col;
        const int pos = ((ks * 4 + quad) ^ (row & 7)) * 8;
        bh[nt] = *(const short8*)&Bh[row * 64 + pos];
        if (t3) bl[nt] = *(const short8*)&Bl[row * 64 + pos];
      }
#pragma unroll
      for (int mt = 0; mt < 2; ++mt)
#pragma unroll
        for (int nt = 0; nt < 2; ++nt) {
          acc[mt][nt] = MFMA16(ah[mt], bh[nt], acc[mt][nt]);
          acc[mt][nt] = MFMA16(al[mt], bh[nt], acc[mt][nt]);
          if (t3) acc[mt][nt] = MFMA16(ah[mt], bl[nt], acc[mt][nt]);
        }
    }
    __syncthreads();
  }
#pragma unroll
  for (int nt = 0; nt < 2; ++nt) {
    const int n = n0 + wc + nt * 16 + col;
    const float bb = A.bias[n];
#pragma unroll
    for (int mt = 0; mt < 2; ++mt)
#pragma unroll
      for (int r = 0; r < 4; ++r)
        gemm_store(A, m0 + wr + mt * 16 + quad * 4 + r, n, acc[mt][nt][r] + bb);
  }
}

// ---------------------------------------------------------------------------
// Flash CoPE attention (round-7 proven). 256-thr blocks = 4 waves x 16 q-rows.
// K/V tiles LDS-staged via DMA (double-buffered, XOR-swizzled). Key tiles
// last->first. CLAMP FAST-PATH: once carry >= 63 (all rows), every remaining
// pos clamps to 63 exactly -> p = exp(s + lis[63]).
// Epilogue writes AO hi/lo planes for the 3-term output GEMM.
// ---------------------------------------------------------------------------
__global__ __launch_bounds__(256, 2)
void cope_attn_mfma(const short* __restrict__ Qhi, const short* __restrict__ Qlo,
                    const short* __restrict__ Khi, const short* __restrict__ Vthi,
                    const short* __restrict__ peT,
                    short* __restrict__ AOhi, short* __restrict__ AOlo) {
  __shared__ __align__(16) short Klds[2][4096];
  __shared__ __align__(16) short Vlds[2][4096];
  __shared__ __align__(16) short Phi[4][16][72];
  __shared__ float2 lis2[4][16][65];
  const int tid = threadIdx.x;
  const int w = tid >> 6, lane = tid & 63;
  const int col = lane & 15, quad = lane >> 4;
  const int h = blockIdx.x & 15;
  const int q0 = (blockIdx.x >> 4) * 64 + w * 16;

  const short* Kb = Khi + (size_t)h * SEQ * 64;
  const short* Vb = Vthi + (size_t)h * 64 * SEQ;

  const int lrow8 = lane >> 3;
  const int src_c = (lane & 7) ^ lrow8;

  auto stage = [&](int kt, int buf) {
#pragma unroll
    for (int i = 0; i < 2; ++i) {
      const int inst = 2 * w + i;
      const int row = inst * 8 + lrow8;
      ASYNC16(Kb + (size_t)(kt * 64 + row) * 64 + src_c * 8, &Klds[buf][inst * 512]);
      ASYNC16(Vb + (size_t)row * SEQ + kt * 64 + src_c * 8, &Vlds[buf][inst * 512]);
    }
  };

  short8 qB[2][2];
#pragma unroll
  for (int ks = 0; ks < 2; ++ks) {
    qB[ks][0] = *(const short8*)(Qhi + (size_t)(h * SEQ + q0 + col) * 64 + ks * 32 + quad * 8);
    qB[ks][1] = *(const short8*)(Qlo + (size_t)(h * SEQ + q0 + col) * 64 + ks * 32 + quad * 8);
  }

  stage(31, 0);

  {
    floatx4 li[4] = {};
#pragma unroll
    for (int nt = 0; nt < 4; ++nt)
#pragma unroll
      for (int ks = 0; ks < 2; ++ks) {
        short8 pb = *(const short8*)(peT + (nt * 16 + col) * 64 + ks * 32 + quad * 8);
        li[nt] = MFMA16(qB[ks][0], pb, li[nt]);
        li[nt] = MFMA16(qB[ks][1], pb, li[nt]);
      }
#pragma unroll
    for (int nt = 0; nt < 4; ++nt)
#pragma unroll
      for (int r = 0; r < 4; ++r) {
        const int qr = quad * 4 + r;
        const int pos = nt * 16 + col;
        const float v = li[nt][r];
        lis2[w][qr][pos].x = v;
        if (pos > 0) lis2[w][qr][pos - 1].y = v;
        if (pos == 63) lis2[w][qr][63].y = v;
      }
  }
  __syncthreads();
  const float lis63 = lis2[w][col][63].x;

  float lrow = 0.f;
  float carry = 0.f;
  bool fast = false;
  floatx4 O[4] = {};

  const int swz = col & 7;

#pragma unroll 1
  for (int it = 0; it < 32; ++it) {
    const int kt = 31 - it;
    const int buf = it & 1;
    if (kt > 0) stage(kt - 1, buf ^ 1);

    short8 kf[4][2], vf[2][4];
#pragma unroll
    for (int ksub = 0; ksub < 4; ++ksub)
#pragma unroll
      for (int ks = 0; ks < 2; ++ks)
        kf[ksub][ks] =
            *(const short8*)&Klds[buf][(ksub * 16 + col) * 64 + (((ks * 4 + quad) ^ swz) * 8)];
#pragma unroll
    for (int ks = 0; ks < 2; ++ks)
#pragma unroll
      for (int dt = 0; dt < 4; ++dt)
        vf[ks][dt] =
            *(const short8*)&Vlds[buf][(dt * 16 + col) * 64 + (((ks * 4 + quad) ^ swz) * 8)];

    floatx4 S[4] = {};
#pragma unroll
    for (int ksub = 0; ksub < 4; ++ksub)
#pragma unroll
      for (int ks = 0; ks < 2; ++ks) {
        S[ksub] = MFMA16(kf[ksub][ks], qB[ks][0], S[ksub]);
        S[ksub] = MFMA16(kf[ksub][ks], qB[ks][1], S[ksub]);
      }
    float sv[4][4];
#pragma unroll
    for (int ksub = 0; ksub < 4; ++ksub)
#pragma unroll
      for (int r = 0; r < 4; ++r) sv[ksub][r] = S[ksub][r] * 0.125f;

    if (!fast && __all((int)(carry >= 63.0f))) fast = true;

    float p4[4][4];
    if (fast) {
#pragma unroll
      for (int ksub = 0; ksub < 4; ++ksub)
#pragma unroll
        for (int r = 0; r < 4; ++r) {
          float pr = __expf(sv[ksub][r] + lis63);
          p4[ksub][r] = pr;
          lrow += pr;
        }
    } else {
      float g[4][4];
#pragma unroll
      for (int ksub = 0; ksub < 4; ++ksub)
#pragma unroll
        for (int r = 0; r < 4; ++r)
          g[ksub][r] = __builtin_amdgcn_rcpf(1.0f + __expf(-sv[ksub][r]));
      float l[4][4], S4[4];
#pragma unroll
      for (int ksub = 0; ksub < 4; ++ksub) {
        l[ksub][3] = g[ksub][3];
        l[ksub][2] = l[ksub][3] + g[ksub][2];
        l[ksub][1] = l[ksub][2] + g[ksub][1];
        l[ksub][0] = l[ksub][1] + g[ksub][0];
        S4[ksub] = l[ksub][0];
      }
      float Sq[4], T[4];
#pragma unroll
      for (int ksub = 0; ksub < 4; ++ksub) {
        float d16 = __shfl_down(S4[ksub], 16, 64);
        float d32 = __shfl_down(S4[ksub], 32, 64);
        float d48 = __shfl_down(S4[ksub], 48, 64);
        float u16 = __shfl_up(S4[ksub], 16, 64);
        float u32 = __shfl_up(S4[ksub], 32, 64);
        float u48 = __shfl_up(S4[ksub], 48, 64);
        float sq = ((quad < 3) ? d16 : 0.f) + ((quad < 2) ? d32 : 0.f) + ((quad < 1) ? d48 : 0.f);
        float pq = ((quad > 0) ? u16 : 0.f) + ((quad > 1) ? u32 : 0.f) + ((quad > 2) ? u48 : 0.f);
        Sq[ksub] = sq;
        T[ksub] = pq + S4[ksub] + sq;
      }
      float U[4];
      U[3] = carry;
      U[2] = U[3] + T[3];
      U[1] = U[2] + T[2];
      U[0] = U[1] + T[1];
      carry = U[0] + T[0];
#pragma unroll
      for (int ksub = 0; ksub < 4; ++ksub)
#pragma unroll
        for (int r = 0; r < 4; ++r) {
          float p = fminf(U[ksub] + Sq[ksub] + l[ksub][r], 63.0f);
          float pf = floorf(p);
          int fi = (int)pf;
          float wq = p - pf;
          float2 lfc = lis2[w][col][fi];
          float pr = __expf(sv[ksub][r] + lfc.x + wq * (lfc.y - lfc.x));
          p4[ksub][r] = pr;
          lrow += pr;
        }
    }
#pragma unroll
    for (int ksub = 0; ksub < 4; ++ksub)
#pragma unroll
      for (int rp = 0; rp < 2; ++rp) {
        short h0 = f2bf(p4[ksub][2 * rp]);
        short h1 = f2bf(p4[ksub][2 * rp + 1]);
        *(int*)&Phi[w][col][ksub * 16 + quad * 4 + 2 * rp] =
            (unsigned short)h0 | ((unsigned)(unsigned short)h1 << 16);
      }
    short8 pa[2];
#pragma unroll
    for (int ks = 0; ks < 2; ++ks)
      pa[ks] = *(const short8*)&Phi[w][col][ks * 32 + quad * 8];
#pragma unroll
    for (int ks = 0; ks < 2; ++ks)
#pragma unroll
      for (int dt = 0; dt < 4; ++dt)
        O[dt] = MFMA16(pa[ks], vf[ks][dt], O[dt]);

    __syncthreads();
  }

  float lr = lrow;
  lr += __shfl_xor(lr, 16, 64);
  lr += __shfl_xor(lr, 32, 64);
  float inv[4];
#pragma unroll
  for (int r = 0; r < 4; ++r) inv[r] = 1.0f / __shfl(lr, quad * 4 + r, 64);
#pragma unroll
  for (int dt = 0; dt < 4; ++dt)
#pragma unroll
    for (int r = 0; r < 4; ++r) {
      float val = O[dt][r] * inv[r];
      int q = q0 + quad * 4 + r;
      int cg = h * 64 + dt * 16 + col;
      short hi = f2bf(val), lo = f2bf(val - bf2f(hi));
      AOhi[(size_t)q * 1024 + cg] = hi;
      AOlo[(size_t)q * 1024 + cg] = lo;
    }
}

// ---------------------------------------------------------------------------
// fp32 fallback (used only if ws_size is too small)
// ---------------------------------------------------------------------------
template <int MODE>
__global__ __launch_bounds__(256)
void gemm_bt_f32(const float* __restrict__ X, const float* __restrict__ W,
                 const float* __restrict__ bias, float* __restrict__ C,
                 int M, int N, int K) {
  __shared__ __align__(16) float Xs[16][68];
  __shared__ __align__(16) float Ws[16][68];
  const int t = threadIdx.x;
  const int tx = t & 15, ty = t >> 4;
  const int m0 = blockIdx.x * 64, n0 = blockIdx.y * 64;
  const int r = t >> 2;
  const int c4 = (t & 3) << 2;
  const float* Xp = X + (size_t)(m0 + r) * K + c4;
  const float* Wp = W + (size_t)(n0 + r) * K + c4;
  float acc[4][4] = {};
  for (int k0 = 0; k0 < K; k0 += 16) {
    float4 xv = *(const float4*)(Xp + k0);
    float4 wv = *(const float4*)(Wp + k0);
    __syncthreads();
    Xs[c4 + 0][r] = xv.x; Xs[c4 + 1][r] = xv.y; Xs[c4 + 2][r] = xv.z; Xs[c4 + 3][r] = xv.w;
    Ws[c4 + 0][r] = wv.x; Ws[c4 + 1][r] = wv.y; Ws[c4 + 2][r] = wv.z; Ws[c4 + 3][r] = wv.w;
    __syncthreads();
#pragma unroll
    for (int k = 0; k < 16; ++k) {
      const float4 xr = *(const float4*)&Xs[k][ty << 2];
      const float4 wr = *(const float4*)&Ws[k][tx << 2];
      const float xa[4] = {xr.x, xr.y, xr.z, xr.w};
      const float wa[4] = {wr.x, wr.y, wr.z, wr.w};
#pragma unroll
      for (int i = 0; i < 4; ++i)
#pragma unroll
        for (int j = 0; j < 4; ++j) acc[i][j] += xa[i] * wa[j];
    }
  }
#pragma unroll
  for (int i = 0; i < 4; ++i) {
    const int m = m0 + (ty << 2) + i;
#pragma unroll
    for (int j = 0; j < 4; ++j) {
      const int n = n0 + (tx << 2) + j;
      const float v = acc[i][j] + bias[n];
      if (MODE == 0) C[(size_t)m * N + n] = v;
      else { const int hh = n >> 6, d = n & 63; C[((size_t)hh * SEQ + m) * HD + d] = v; }
    }
  }
}

__global__ __launch_bounds__(256)
void cope_attn_f32(const float* __restrict__ Qh, const float* __restrict__ Kh,
                   const float* __restrict__ Vh, const float* __restrict__ pe,
                   float* __restrict__ AO) {
  __shared__ float Kt[64][65];
  __shared__ float Vt[64][65];
  __shared__ float lis[16][64];
  const int t = threadIdx.x;
  const int lane = t & 63;
  const int w = t >> 6;
  const int h = blockIdx.y;
  const int qbase = blockIdx.x * 16 + w * 4;
  float qreg[4];
#pragma unroll
  for (int rr = 0; rr < 4; ++rr)
    qreg[rr] = Qh[((size_t)h * SEQ + qbase + rr) * HD + lane];
  float li[4] = {0.f, 0.f, 0.f, 0.f};
  for (int d = 0; d < 64; ++d) {
    const float pv = pe[d * NPOSN + lane];
#pragma unroll
    for (int rr = 0; rr < 4; ++rr) li[rr] += lane_bcast(qreg[rr], d) * pv;
  }
#pragma unroll
  for (int rr = 0; rr < 4; ++rr) lis[w * 4 + rr][lane] = li[rr];
  float mrow[4] = {-1e30f, -1e30f, -1e30f, -1e30f};
  float lrow[4] = {0.f, 0.f, 0.f, 0.f};
  float carry[4] = {0.f, 0.f, 0.f, 0.f};
  float acc[4] = {0.f, 0.f, 0.f, 0.f};
  for (int kt = (SEQ / 64) - 1; kt >= 0; --kt) {
    const int k0 = kt * 64;
    __syncthreads();
#pragma unroll
    for (int i = 0; i < 4; ++i) {
      const int lin = t + i * 256;
      const int row = lin >> 4, cc = (lin & 15) << 2;
      const float4 kv = *(const float4*)(Kh + ((size_t)h * SEQ + k0 + row) * HD + cc);
      Kt[row][cc + 0] = kv.x; Kt[row][cc + 1] = kv.y; Kt[row][cc + 2] = kv.z; Kt[row][cc + 3] = kv.w;
      const float4 vv = *(const float4*)(Vh + ((size_t)h * SEQ + k0 + row) * HD + cc);
      Vt[row][cc + 0] = vv.x; Vt[row][cc + 1] = vv.y; Vt[row][cc + 2] = vv.z; Vt[row][cc + 3] = vv.w;
    }
    __syncthreads();
    float svv[4] = {0.f, 0.f, 0.f, 0.f};
#pragma unroll
    for (int d = 0; d < 64; ++d) {
      const float kd = Kt[lane][d];
#pragma unroll
      for (int rr = 0; rr < 4; ++rr) svv[rr] += lane_bcast(qreg[rr], d) * kd;
    }
    float p4[4], scl[4];
#pragma unroll
    for (int rr = 0; rr < 4; ++rr) {
      const float s = svv[rr] * 0.125f;
      const float gg = 1.0f / (1.0f + __expf(-s));
      float gs = gg;
#pragma unroll
      for (int off = 1; off < 64; off <<= 1) {
        const float tt = __shfl_down(gs, off, 64);
        gs += (lane + off < 64) ? tt : 0.0f;
      }
      const float tot = lane_bcast(gs, 0);
      float p = carry[rr] + gs;
      carry[rr] += tot;
      p = fminf(p, 63.0f);
      const float pf = floorf(p);
      const float wq = p - pf;
      const int fi = (int)pf;
      const int ci = (int)ceilf(p);
      const float cope = lis[w * 4 + rr][ci] * wq + lis[w * 4 + rr][fi] * (1.0f - wq);
      const float av = s + cope;
      float mt = av;
#pragma unroll
      for (int off = 32; off > 0; off >>= 1) mt = fmaxf(mt, __shfl_xor(mt, off, 64));
      const float nm = fmaxf(mrow[rr], mt);
      const float sc = __expf(mrow[rr] - nm);
      const float p2 = __expf(av - nm);
      float psum = p2;
#pragma unroll
      for (int off = 32; off > 0; off >>= 1) psum += __shfl_xor(psum, off, 64);
      lrow[rr] = lrow[rr] * sc + psum;
      mrow[rr] = nm;
      p4[rr] = p2;
      scl[rr] = sc;
    }
#pragma unroll
    for (int rr = 0; rr < 4; ++rr) acc[rr] *= scl[rr];
#pragma unroll
    for (int j = 0; j < 64; ++j) {
      const float vj = Vt[j][lane];
#pragma unroll
      for (int rr = 0; rr < 4; ++rr) acc[rr] += lane_bcast(p4[rr], j) * vj;
    }
  }
#pragma unroll
  for (int rr = 0; rr < 4; ++rr)
    AO[(size_t)(qbase + rr) * ND + h * HD + lane] = acc[rr] / lrow[rr];
}

// ---------------------------------------------------------------------------
extern "C" void kernel_launch(void* const* d_in, const int* in_sizes, int n_in,
                              void* d_out, int out_size, void* d_ws, size_t ws_size,
                              hipStream_t stream) {
  (void)in_sizes; (void)n_in; (void)out_size;
  const float* q    = (const float*)d_in[0];
  const float* k    = (const float*)d_in[1];
  const float* v    = (const float*)d_in[2];
  const float* Wq_w = (const float*)d_in[3];
  const float* Wq_b = (const float*)d_in[4];
  const float* Wk_w = (const float*)d_in[5];
  const float* Wk_b = (const float*)d_in[6];
  const float* Wv_w = (const float*)d_in[7];
  const float* Wv_b = (const float*)d_in[8];
  const float* Wo_w = (const float*)d_in[9];
  const float* Wo_b = (const float*)d_in[10];
  const float* pe   = (const float*)d_in[11];
  float* out = (float*)d_out;
  char* ws = (char*)d_ws;

  const size_t XP = (size_t)SEQ * 1024 * 2;   // 4 MB per activation plane
  const size_t WP = (size_t)1024 * 1024 * 2;  // 2 MB per weight plane
  const size_t HB = (size_t)SEQ * 1024 * 2;   // 4 MB per head buffer
  const size_t NEED = 6 * XP + 8 * WP + 4 * HB + 8192;

  if (ws_size >= NEED) {
    short* Xqh = (short*)ws;               short* Xql = (short*)(ws + XP);
    short* Xkh = (short*)(ws + 2 * XP);    short* Xkl = (short*)(ws + 3 * XP);
    short* Xvh = (short*)(ws + 4 * XP);    short* Xvl = (short*)(ws + 5 * XP);
    char*  wb  = ws + 6 * XP;
    short* Wqh = (short*)wb;               short* Wql = (short*)(wb + WP);
    short* Wkh = (short*)(wb + 2 * WP);    short* Wkl = (short*)(wb + 3 * WP);
    short* Wvh = (short*)(wb + 4 * WP);    short* Wvl = (short*)(wb + 5 * WP);
    short* Woh = (short*)(wb + 6 * WP);    short* Wol = (short*)(wb + 7 * WP);
    char*  hb  = wb + 8 * WP;
    short* Qhi = (short*)hb;               short* Qlo = (short*)(hb + HB);
    short* Khi = (short*)(hb + 2 * HB);    short* Vthi = (short*)(hb + 3 * HB);
    short* peT = (short*)(hb + 4 * HB);
    short* AOhi = Xqh;                     // reuse after projections
    short* AOlo = Xql;

    Prep2 P{q, Xqh, Xql, k, Xkh, Xkl, v, Xvh, Xvl,
            Wq_w, Wqh, Wql, Wk_w, Wkh, Wkl, Wv_w, Wvh, Wvl, Wo_w, Woh, Wol,
            pe, peT};
    prep2<<<dim3(2048, 1, 8), 256, 0, stream>>>(P);
    GArg2 aq{Xqh, Xql, Wqh, Wql, Wq_b, Qhi, Qlo, 1};           // 3-term
    GArg2 ak{Xkh, Xkl, Wkh, nullptr, Wk_b, Khi, nullptr, 1};   // 2-term, hi only
    GArg2 av{Xvh, Xvl, Wvh, nullptr, Wv_b, Vthi, nullptr, 2};  // 2-term, transposed
    gemm_planes<<<dim3(16, 16, 3), 256, 0, stream>>>(aq, ak, av);
    cope_attn_mfma<<<512, 256, 0, stream>>>(Qhi, Qlo, Khi, Vthi, peT, AOhi, AOlo);
    GArg2 ao{AOhi, AOlo, Woh, Wol, Wo_b, (void*)out, nullptr, 0};   // 3-term fp32 out
    gemm_planes64<<<dim3(32, 16), 256, 0, stream>>>(ao);
  } else {
    const size_t per = (size_t)NH * SEQ * HD;
    float* Qh = (float*)d_ws;
    float* Kh = Qh + per;
    float* Vh = Kh + per;
    float* AO = Vh + per;
    dim3 gblk(256), ggrd(SEQ / 64, ND / 64);
    gemm_bt_f32<1><<<ggrd, gblk, 0, stream>>>(q, Wq_w, Wq_b, Qh, SEQ, ND, ND);
    gemm_bt_f32<1><<<ggrd, gblk, 0, stream>>>(k, Wk_w, Wk_b, Kh, SEQ, ND, ND);
    gemm_bt_f32<1><<<ggrd, gblk, 0, stream>>>(v, Wv_w, Wv_b, Vh, SEQ, ND, ND);
    cope_attn_f32<<<dim3(SEQ / 16, NH), 256, 0, stream>>>(Qh, Kh, Vh, pe, AO);
    gemm_bt_f32<0><<<ggrd, gblk, 0, stream>>>(AO, Wo_w, Wo_b, out, SEQ, ND, ND);
  }
}